// Round 3
// baseline (1321.233 us; speedup 1.0000x reference)
//
#include <hip/hip_runtime.h>

// ---------------- problem constants ----------------
#define M_DIM 8192   // B*S = 4*2048
#define N_DIM 16384  // OUT
#define K_DIM 4096   // IN
#define QBLK  64     // bnb quant block

// GEMM geometry: 256x256 tile, BK=32, quad-buffered LDS (4 x 32 KiB)
#define BM 256
#define BN 256
#define BK 32
#define NT (K_DIM / BK)   // 128 K-tiles

typedef short  s8v  __attribute__((ext_vector_type(8)));   // 8 bf16 (MFMA A/B frag)
typedef unsigned short u16x8 __attribute__((ext_vector_type(8)));
typedef float  f4v  __attribute__((ext_vector_type(4)));   // MFMA C/D frag

__constant__ float NF4C[16] = {
    -1.0f, -0.6961928009986877f, -0.5250730514526367f, -0.39491748809814453f,
    -0.28444138169288635f, -0.18477343022823334f, -0.09105003625154495f, 0.0f,
    0.07958029955625534f, 0.16093020141124725f, 0.24611230194568634f, 0.33791524171829224f,
    0.44070982933044434f, 0.5626170039176941f, 0.7229568362236023f, 1.0f
};

// round-to-nearest-even f32 -> bf16 bits (finite inputs only)
__device__ __forceinline__ unsigned short f2bf(float f) {
    union { float f; unsigned u; } v; v.f = f;
    unsigned r = v.u + 0x7FFFu + ((v.u >> 16) & 1u);
    return (unsigned short)(r >> 16);
}

__device__ __forceinline__ void async16(const unsigned short* g, unsigned short* l) {
    __builtin_amdgcn_global_load_lds(
        (const __attribute__((address_space(1))) void*)g,
        (__attribute__((address_space(3))) void*)l,
        16, 0, 0);
}

#define WAITVM(n)  asm volatile("s_waitcnt vmcnt(" #n ")" ::: "memory")
#define WAIT_LGKM0 asm volatile("s_waitcnt lgkmcnt(0)" ::: "memory")
#define BAR()      __builtin_amdgcn_s_barrier()

// ---------------- prep pass 1: x fp32 -> bf16 ----------------
__global__ void convert_x_kernel(const float* __restrict__ x,
                                 unsigned short* __restrict__ o, long n) {
    long i = ((long)blockIdx.x * blockDim.x + threadIdx.x) * 8;
    long stride = (long)gridDim.x * blockDim.x * 8;
    for (; i < n; i += stride) {
        const float4* p = (const float4*)(x + i);
        float4 a = p[0], b = p[1];
        u16x8 o8;
        o8[0] = f2bf(a.x); o8[1] = f2bf(a.y); o8[2] = f2bf(a.z); o8[3] = f2bf(a.w);
        o8[4] = f2bf(b.x); o8[5] = f2bf(b.y); o8[6] = f2bf(b.z); o8[7] = f2bf(b.w);
        *(u16x8*)(o + i) = o8;
    }
}

// ---------------- prep pass 2: NF4 codes -> bf16 weights ----------------
__global__ void dequant_w_kernel(const int* __restrict__ codes,
                                 const float* __restrict__ am,
                                 unsigned short* __restrict__ o, long n) {
    __shared__ float lut[16];
    if (threadIdx.x < 16) lut[threadIdx.x] = NF4C[threadIdx.x];
    __syncthreads();
    long i = ((long)blockIdx.x * blockDim.x + threadIdx.x) * 8;
    long stride = (long)gridDim.x * blockDim.x * 8;
    for (; i < n; i += stride) {
        const int4* p = (const int4*)(codes + i);
        int4 c0 = p[0], c1 = p[1];
        float s = am[i >> 6];
        u16x8 o8;
        o8[0] = f2bf(lut[c0.x] * s); o8[1] = f2bf(lut[c0.y] * s);
        o8[2] = f2bf(lut[c0.z] * s); o8[3] = f2bf(lut[c0.w] * s);
        o8[4] = f2bf(lut[c1.x] * s); o8[5] = f2bf(lut[c1.y] * s);
        o8[6] = f2bf(lut[c1.z] * s); o8[7] = f2bf(lut[c1.w] * s);
        *(u16x8*)(o + i) = o8;
    }
}

// ---------------- deep-pipelined 256x256 GEMM, BK=32, 4 LDS buffers ----------------
// y[m][n] = sum_k A[m][k]*B[n][k]; A [M][K], B [N][K] bf16 row-major.
// 512 threads = 8 waves (wm 0..1 x wn 0..3); per-wave output 128x64.
// LDS: 4 bufs x {A0,A1,B0,B1} halves x 8 KiB = 128 KiB. Half = 128 rows x 32 k,
// stored as 8 subtiles (16 rows) of [kg 0..3][row 0..15] 16B chunks ->
// conflict-free ds_read_b128 + linear global_load_lds dest (1 load/thread/half,
// inverse-mapped per-lane global source).
// Per tile: 2 phases x 16 MFMA. Prefetch tile t+3 during tile t (issue A0,B0
// at ph0; B1,A1 at ph1). Per-wave vmcnt ledger (1 instr per STAGE):
//   ph0-end needs A1^t     (issued t-3 ph1): younger = 4+4+2  -> vmcnt(10)
//   ph1-end needs B1^{t+1} (issued t-2 ph1): younger = 1+4+2+2 -> vmcnt(9)
// Tail (no staging for t+3 >= NT): t=NT-3 (8,5), t=NT-2 (4,1), t=NT-1 (0,skip).
__global__ __launch_bounds__(512, 2)
void gemm_deep_kernel(const unsigned short* __restrict__ A,
                      const unsigned short* __restrict__ B,
                      float* __restrict__ Cp) {
    __shared__ __attribute__((aligned(16))) unsigned short lds[65536]; // 128 KiB

    const int tid  = threadIdx.x;
    const int wid  = tid >> 6;
    const int lane = tid & 63;
    const int wm   = wid >> 2;   // 0..1
    const int wn   = wid & 3;    // 0..3
    const int fr   = lane & 15;
    const int kg   = lane >> 4;

    // XCD-bijective swizzle: nwg = 32*64 = 2048, 8 XCDs, chunk 256
    const int bid = blockIdx.x;
    const int wg  = (bid & 7) * 256 + (bid >> 3);
    const int bm0 = (wg >> 6) * BM;
    const int bn0 = (wg & 63) * BN;

    // staging source: thread (wid,lane) covers half-region byte wid*1024+lane*16
    // = subtile wid, k-chunk kg, row fr  ->  global (row = wid*16+fr, col = kg*8)
    const int srow = wid * 16 + fr;
    const int scol = kg * 8;
    const unsigned short* pA0 = A + (size_t)(bm0 + srow) * K_DIM + scol;
    const unsigned short* pA1 = pA0 + (size_t)128 * K_DIM;
    const unsigned short* pB0 = B + (size_t)(bn0 + srow) * K_DIM + scol;
    const unsigned short* pB1 = pB0 + (size_t)128 * K_DIM;

    // halves: A0=0, A1=1, B0=2, B1=3 ; region shorts off = buf*16384 + half*4096
#define STAGE(bufI, half, P) \
    { async16(P, lds + (bufI) * 16384 + (half) * 4096 + wid * 512); P += BK; }

    const char* ldsc = (const char*)lds;
    const int qL = (kg << 8) + (fr << 4);   // [kg][row] chunk within subtile

    f4v acc[8][4];
#pragma unroll
    for (int i = 0; i < 8; ++i)
#pragma unroll
        for (int j = 0; j < 4; ++j) acc[i][j] = f4v{0.f, 0.f, 0.f, 0.f};

    s8v aset[4], b0set[2], b1set[2];

#define RD_A(bb, qm)                                                          \
    { const char* ba = ldsc + (bb) + (qm) * 8192 + wm * 4096 + qL;            \
      aset[0] = *(const s8v*)(ba);                                            \
      aset[1] = *(const s8v*)(ba + 1024);                                     \
      aset[2] = *(const s8v*)(ba + 2048);                                     \
      aset[3] = *(const s8v*)(ba + 3072); }

#define RD_B(bb, qn, BS)                                                      \
    { const char* bp = ldsc + (bb) + 16384 + (qn) * 8192 + wn * 2048 + qL;    \
      BS[0] = *(const s8v*)(bp);                                              \
      BS[1] = *(const s8v*)(bp + 1024); }

#define MM(qm, qn, BS)                                                        \
    _Pragma("unroll") for (int fm = 0; fm < 4; ++fm)                          \
      _Pragma("unroll") for (int fn = 0; fn < 2; ++fn)                        \
        acc[(qm)*4+fm][(qn)*2+fn] = __builtin_amdgcn_mfma_f32_16x16x32_bf16(  \
            aset[fm], BS[fn], acc[(qm)*4+fm][(qn)*2+fn], 0, 0, 0);

#define PH0(bb, DS, W)                                                        \
    RD_A(bb, 0); RD_B(bb, 0, b0set); RD_B(bb, 1, b1set);                      \
    DS;                                                                       \
    BAR(); WAIT_LGKM0;                                                        \
    __builtin_amdgcn_s_setprio(1); MM(0, 0, b0set); MM(0, 1, b1set);          \
    __builtin_amdgcn_s_setprio(0);                                            \
    W; BAR();

#define PH1(bb, DS, W)                                                        \
    RD_A(bb, 1);                                                              \
    DS;                                                                       \
    BAR(); WAIT_LGKM0;                                                        \
    __builtin_amdgcn_s_setprio(1); MM(1, 0, b0set); MM(1, 1, b1set);          \
    __builtin_amdgcn_s_setprio(0);                                            \
    W; BAR();

    // ---- prologue: stage tiles 0,1,2 (issue order A0,B0,B1,A1 per tile) ----
#pragma unroll
    for (int j = 0; j < 3; ++j) {
        STAGE(j, 0, pA0); STAGE(j, 2, pB0); STAGE(j, 3, pB1); STAGE(j, 1, pA1);
    }
    WAITVM(9);   // retire A0,B0,B1 of tile 0; 9 younger remain
    BAR();

    // ---- main loop: tiles 0 .. NT-4 (each stages tile t+3) ----
    for (int t = 0; t < NT - 3; ++t) {
        const int bb = (t & 3) * 32768;      // current buffer, bytes
        const int sb = (t + 3) & 3;          // staging buffer index
        PH0(bb, { STAGE(sb, 0, pA0); STAGE(sb, 2, pB0); }, WAITVM(10));
        PH1(bb, { STAGE(sb, 3, pB1); STAGE(sb, 1, pA1); }, WAITVM(9));
    }
    // ---- tail: t = NT-3, NT-2, NT-1 (no staging; shrinking waits) ----
    {
        const int bb = ((NT - 3) & 3) * 32768;
        PH0(bb, , WAITVM(8));
        PH1(bb, , WAITVM(5));
    }
    {
        const int bb = ((NT - 2) & 3) * 32768;
        PH0(bb, , WAITVM(4));
        PH1(bb, , WAITVM(1));
    }
    {
        const int bb = ((NT - 1) & 3) * 32768;
        PH0(bb, , WAITVM(0));
        PH1(bb, , (void)0);
    }

    // ---- epilogue: D col = lane&15, row = (lane>>4)*4 + r ----
#pragma unroll
    for (int m8 = 0; m8 < 8; ++m8) {
        const int grow = bm0 + (m8 >> 2) * 128 + wm * 64 + (m8 & 3) * 16 + (lane >> 4) * 4;
#pragma unroll
        for (int n4 = 0; n4 < 4; ++n4) {
            const int gcol = bn0 + (n4 >> 1) * 128 + wn * 32 + (n4 & 1) * 16 + (lane & 15);
            float* yp = Cp + (size_t)grow * N_DIM + gcol;
#pragma unroll
            for (int r = 0; r < 4; ++r) yp[(size_t)r * N_DIM] = acc[m8][n4][r];
        }
    }
#undef STAGE
#undef RD_A
#undef RD_B
#undef MM
#undef PH0
#undef PH1
}

// ---------------- fallback: fused dequant GEMM (no workspace needed) ----------------
__global__ void gemm_fused_kernel(const float* __restrict__ X,
                                  const int* __restrict__ W,
                                  const float* __restrict__ am,
                                  float* __restrict__ C) {
    __shared__ __attribute__((aligned(16))) unsigned short ldsA[128 * 32];
    __shared__ __attribute__((aligned(16))) unsigned short ldsB[128 * 32];
    __shared__ float lut[16];

    const int tid = threadIdx.x;
    if (tid < 16) lut[tid] = NF4C[tid];
    __syncthreads();

    const int wave = tid >> 6, lane = tid & 63;
    const int wr = wave >> 1, wc = wave & 1;
    const int bid = blockIdx.x;
    const int wg  = (bid & 7) * 1024 + (bid >> 3);
    const int bm0 = (wg >> 7) * 128;
    const int bn0 = (wg & 127) * 128;

    const int row = tid >> 2, col8 = (tid & 3) * 8;
    const float* gX0 = X + (size_t)(bm0 + row) * K_DIM + col8;
    const float* gX1 = gX0 + (size_t)64 * K_DIM;
    const int*   gW0 = W + (size_t)(bn0 + row) * K_DIM + col8;
    const int*   gW1 = gW0 + (size_t)64 * K_DIM;
    const int amRow0 = (bn0 + row) * (K_DIM / QBLK);
    const int amRow1 = (bn0 + row + 64) * (K_DIM / QBLK);

    unsigned short* sA0 = ldsA + tid * 8;
    unsigned short* sA1 = ldsA + (tid + 256) * 8;
    unsigned short* sB0 = ldsB + tid * 8;
    unsigned short* sB1 = ldsB + (tid + 256) * 8;

    f4v acc[4][4];
#pragma unroll
    for (int i = 0; i < 4; ++i)
#pragma unroll
        for (int j = 0; j < 4; ++j) acc[i][j] = f4v{0.f, 0.f, 0.f, 0.f};

    const int fr = lane & 15, kg = lane >> 4;
    const unsigned short* pa = ldsA + (wr * 64 + fr) * 32 + kg * 8;
    const unsigned short* pb = ldsB + (wc * 64 + fr) * 32 + kg * 8;

    for (int k0 = 0; k0 < K_DIM; k0 += 32) {
        float4 x0a = *(const float4*)(gX0 + k0);
        float4 x0b = *(const float4*)(gX0 + k0 + 4);
        float4 x1a = *(const float4*)(gX1 + k0);
        float4 x1b = *(const float4*)(gX1 + k0 + 4);
        int4 w0a = *(const int4*)(gW0 + k0);
        int4 w0b = *(const int4*)(gW0 + k0 + 4);
        int4 w1a = *(const int4*)(gW1 + k0);
        int4 w1b = *(const int4*)(gW1 + k0 + 4);
        float s0 = am[amRow0 + ((k0 + col8) >> 6)];
        float s1 = am[amRow1 + ((k0 + col8) >> 6)];

        u16x8 A0, A1, B0, B1;
        A0[0] = f2bf(x0a.x); A0[1] = f2bf(x0a.y); A0[2] = f2bf(x0a.z); A0[3] = f2bf(x0a.w);
        A0[4] = f2bf(x0b.x); A0[5] = f2bf(x0b.y); A0[6] = f2bf(x0b.z); A0[7] = f2bf(x0b.w);
        A1[0] = f2bf(x1a.x); A1[1] = f2bf(x1a.y); A1[2] = f2bf(x1a.z); A1[3] = f2bf(x1a.w);
        A1[4] = f2bf(x1b.x); A1[5] = f2bf(x1b.y); A1[6] = f2bf(x1b.z); A1[7] = f2bf(x1b.w);
        B0[0] = f2bf(lut[w0a.x] * s0); B0[1] = f2bf(lut[w0a.y] * s0);
        B0[2] = f2bf(lut[w0a.z] * s0); B0[3] = f2bf(lut[w0a.w] * s0);
        B0[4] = f2bf(lut[w0b.x] * s0); B0[5] = f2bf(lut[w0b.y] * s0);
        B0[6] = f2bf(lut[w0b.z] * s0); B0[7] = f2bf(lut[w0b.w] * s0);
        B1[0] = f2bf(lut[w1a.x] * s1); B1[1] = f2bf(lut[w1a.y] * s1);
        B1[2] = f2bf(lut[w1a.z] * s1); B1[3] = f2bf(lut[w1a.w] * s1);
        B1[4] = f2bf(lut[w1b.x] * s1); B1[5] = f2bf(lut[w1b.y] * s1);
        B1[6] = f2bf(lut[w1b.z] * s1); B1[7] = f2bf(lut[w1b.w] * s1);

        __syncthreads();
        *(u16x8*)sA0 = A0; *(u16x8*)sA1 = A1;
        *(u16x8*)sB0 = B0; *(u16x8*)sB1 = B1;
        __syncthreads();

        s8v a[4], b[4];
#pragma unroll
        for (int i = 0; i < 4; ++i) a[i] = *(const s8v*)(pa + i * 16 * 32);
#pragma unroll
        for (int i = 0; i < 4; ++i) b[i] = *(const s8v*)(pb + i * 16 * 32);
#pragma unroll
        for (int i = 0; i < 4; ++i)
#pragma unroll
            for (int j = 0; j < 4; ++j)
                acc[i][j] = __builtin_amdgcn_mfma_f32_16x16x32_bf16(a[i], b[j], acc[i][j], 0, 0, 0);
    }

    const int row0 = bm0 + wr * 64 + (lane >> 4) * 4;
    const int col0 = bn0 + wc * 64 + (lane & 15);
#pragma unroll
    for (int i = 0; i < 4; ++i)
#pragma unroll
        for (int j = 0; j < 4; ++j) {
            float* yp = C + (size_t)(row0 + i * 16) * N_DIM + col0 + j * 16;
#pragma unroll
            for (int r = 0; r < 4; ++r) yp[(size_t)r * N_DIM] = acc[i][j][r];
        }
}

extern "C" void kernel_launch(void* const* d_in, const int* in_sizes, int n_in,
                              void* d_out, int out_size, void* d_ws, size_t ws_size,
                              hipStream_t stream) {
    const float* x     = (const float*)d_in[0];
    const int*   codes = (const int*)d_in[1];
    const float* am    = (const float*)d_in[2];
    float* y = (float*)d_out;

    const long MK = (long)M_DIM * K_DIM;
    const long NK = (long)N_DIM * K_DIM;
    const size_t need = (size_t)(MK + NK) * sizeof(unsigned short);  // 192 MiB

    if (ws_size >= need) {
        unsigned short* xb = (unsigned short*)d_ws;
        unsigned short* wb = xb + MK;
        convert_x_kernel<<<2048, 256, 0, stream>>>(x, xb, MK);
        dequant_w_kernel<<<2048, 256, 0, stream>>>(codes, am, wb, NK);
        const int ngrid = (M_DIM / BM) * (N_DIM / BN);  // 2048
        gemm_deep_kernel<<<ngrid, 512, 0, stream>>>(xb, wb, y);
    } else {
        const int ngrid = (M_DIM / 128) * (N_DIM / 128); // 8192
        gemm_fused_kernel<<<ngrid, 256, 0, stream>>>(x, codes, am, y);
    }
}

// Round 4
// 1158.816 us; speedup vs baseline: 1.1402x; 1.1402x over previous
//
#include <hip/hip_runtime.h>

// ---------------- problem constants ----------------
#define M_DIM 8192   // B*S = 4*2048
#define N_DIM 16384  // OUT
#define K_DIM 4096   // IN
#define QBLK  64     // bnb quant block

// GEMM geometry: 256x256 tile, BK=64, double-buffered LDS (2 x 64 KiB)
#define BM 256
#define BN 256
#define BK 64
#define NT (K_DIM / BK)   // 64 K-tiles

typedef short  s8v  __attribute__((ext_vector_type(8)));   // 8 bf16 (MFMA A/B frag)
typedef unsigned short u16x8 __attribute__((ext_vector_type(8)));
typedef float  f4v  __attribute__((ext_vector_type(4)));   // MFMA C/D frag

__constant__ float NF4C[16] = {
    -1.0f, -0.6961928009986877f, -0.5250730514526367f, -0.39491748809814453f,
    -0.28444138169288635f, -0.18477343022823334f, -0.09105003625154495f, 0.0f,
    0.07958029955625534f, 0.16093020141124725f, 0.24611230194568634f, 0.33791524171829224f,
    0.44070982933044434f, 0.5626170039176941f, 0.7229568362236023f, 1.0f
};

// round-to-nearest-even f32 -> bf16 bits (finite inputs only)
__device__ __forceinline__ unsigned short f2bf(float f) {
    union { float f; unsigned u; } v; v.f = f;
    unsigned r = v.u + 0x7FFFu + ((v.u >> 16) & 1u);
    return (unsigned short)(r >> 16);
}

__device__ __forceinline__ void async16(const unsigned short* g, unsigned short* l) {
    __builtin_amdgcn_global_load_lds(
        (const __attribute__((address_space(1))) void*)g,
        (__attribute__((address_space(3))) void*)l,
        16, 0, 0);
}

#define WAITVM(n)  asm volatile("s_waitcnt vmcnt(" #n ")" ::: "memory")
#define BARX()     asm volatile("s_barrier" ::: "memory")

// ---------------- prep pass 1: x fp32 -> bf16 ----------------
__global__ void convert_x_kernel(const float* __restrict__ x,
                                 unsigned short* __restrict__ o, long n) {
    long i = ((long)blockIdx.x * blockDim.x + threadIdx.x) * 8;
    long stride = (long)gridDim.x * blockDim.x * 8;
    for (; i < n; i += stride) {
        const float4* p = (const float4*)(x + i);
        float4 a = p[0], b = p[1];
        u16x8 o8;
        o8[0] = f2bf(a.x); o8[1] = f2bf(a.y); o8[2] = f2bf(a.z); o8[3] = f2bf(a.w);
        o8[4] = f2bf(b.x); o8[5] = f2bf(b.y); o8[6] = f2bf(b.z); o8[7] = f2bf(b.w);
        *(u16x8*)(o + i) = o8;
    }
}

// ---------------- prep pass 2: NF4 codes -> bf16 weights ----------------
__global__ void dequant_w_kernel(const int* __restrict__ codes,
                                 const float* __restrict__ am,
                                 unsigned short* __restrict__ o, long n) {
    __shared__ float lut[16];
    if (threadIdx.x < 16) lut[threadIdx.x] = NF4C[threadIdx.x];
    __syncthreads();
    long i = ((long)blockIdx.x * blockDim.x + threadIdx.x) * 8;
    long stride = (long)gridDim.x * blockDim.x * 8;
    for (; i < n; i += stride) {
        const int4* p = (const int4*)(codes + i);
        int4 c0 = p[0], c1 = p[1];
        float s = am[i >> 6];
        u16x8 o8;
        o8[0] = f2bf(lut[c0.x] * s); o8[1] = f2bf(lut[c0.y] * s);
        o8[2] = f2bf(lut[c0.z] * s); o8[3] = f2bf(lut[c0.w] * s);
        o8[4] = f2bf(lut[c1.x] * s); o8[5] = f2bf(lut[c1.y] * s);
        o8[6] = f2bf(lut[c1.z] * s); o8[7] = f2bf(lut[c1.w] * s);
        *(u16x8*)(o + i) = o8;
    }
}

// ---------------- 3-phase 256x256 GEMM (round-2 geometry, merged barriers) ----
// y[m][n] = sum_k A[m][k]*B[n][k]; A [M][K], B [N][K] bf16 row-major.
// 512 threads = 8 waves (wm 0..1 x wn 0..3); per-wave output 128x64 as
// quadrants (qm,qn). LDS: 2 buf x {A0,A1,B0,B1} halves, 16 KiB each = 128 KiB.
// Half region: 16 subtiles (16 rows x 32 k) of 1024 B; within a subtile 16B
// chunks stored [kg][row] -> conflict-free ds_read_b128; staged linearly by
// global_load_lds with inverse-mapped per-lane global SOURCE address.
// Phases per K-tile (ONE barrier per phase, at the end, after a counted wait;
// no explicit lgkm drain -- compiler inserts fine-grained lgkmcnt):
//   ph0 : RD A0,B0 | STAGE A0' | MM(0,0) | vmcnt(4) | bar
//   ph1 : RD B1    | STAGE B0' | MM(0,1) | vmcnt(4) | bar
//   ph23: RD A1    | STAGE B1' | MM(1,1) | STAGE A1' | MM(1,0) | vmcnt(4) | bar
// Ledger (2 instr/STAGE): each vmcnt(4) retires exactly the halves the next
// phase reads (B1^t / A1^t / A0',B0' of t+1); leads 2-3 phases. Tail: (2,0).
// WAR: stages write regions last read >=4 barriers earlier.
__global__ __launch_bounds__(512, 2)
void gemm_3phase_kernel(const unsigned short* __restrict__ A,
                        const unsigned short* __restrict__ B,
                        float* __restrict__ Cp) {
    __shared__ __attribute__((aligned(16))) unsigned short lds[65536]; // 128 KiB

    const int tid  = threadIdx.x;
    const int wid  = tid >> 6;
    const int lane = tid & 63;
    const int wm   = wid >> 2;   // 0..1
    const int wn   = wid & 3;    // 0..3

    // XCD-bijective swizzle: nwg = 32*64 = 2048, 8 XCDs, chunk 256
    const int bid = blockIdx.x;
    const int wg  = (bid & 7) * 256 + (bid >> 3);
    const int bm0 = (wg >> 6) * BM;
    const int bn0 = (wg & 63) * BN;

    // staging coords: thread covers half-region bytes tid*16 and 8192+tid*16;
    // invert the subtile layout to get (row, kcol).
    int Rr[2], Cc[2];
#pragma unroll
    for (int i = 0; i < 2; ++i) {
        int p = i * 8192 + tid * 16;
        int s = p >> 10, q = p & 1023;
        int kg = q >> 8, r = (q >> 4) & 15;
        Rr[i] = (s >> 1) * 16 + r;          // row in half (0..127)
        Cc[i] = (s & 1) * 32 + kg * 8;      // k col (0..63)
    }
    const unsigned short* pA0[2]; const unsigned short* pA1[2];
    const unsigned short* pB0[2]; const unsigned short* pB1[2];
#pragma unroll
    for (int i = 0; i < 2; ++i) {
        pA0[i] = A + (size_t)(bm0 + Rr[i]) * K_DIM + Cc[i];
        pA1[i] = pA0[i] + (size_t)128 * K_DIM;
        pB0[i] = B + (size_t)(bn0 + Rr[i]) * K_DIM + Cc[i];
        pB1[i] = pB0[i] + (size_t)128 * K_DIM;
    }

#define STAGE(regionIdx, PP)                                                  \
    { unsigned short* d = lds + (regionIdx) * 8192 + wid * 512;               \
      async16(PP[0], d);                                                      \
      async16(PP[1], d + 4096);                                               \
      PP[0] += BK; PP[1] += BK; }

    const int qL = ((lane >> 4) << 8) + ((lane & 15) << 4);  // [kg][row] chunk
    const char* ldsc = (const char*)lds;

    f4v acc[8][4];
#pragma unroll
    for (int i = 0; i < 8; ++i)
#pragma unroll
        for (int j = 0; j < 4; ++j) acc[i][j] = f4v{0.f, 0.f, 0.f, 0.f};

    s8v aset[4][2], b0set[2][2], b1set[2][2];

#define RD_A(qm)                                                              \
    { const char* ba = ldsc + (buf4 + (qm)) * 16384 + wm * 8192 + qL;         \
      _Pragma("unroll") for (int fm = 0; fm < 4; ++fm)                        \
        _Pragma("unroll") for (int kk = 0; kk < 2; ++kk)                      \
          aset[fm][kk] = *(const s8v*)(ba + fm * 2048 + kk * 1024); }

#define RD_B(qn, BS)                                                          \
    { const char* bb = ldsc + (buf4 + 2 + (qn)) * 16384 + wn * 4096 + qL;     \
      _Pragma("unroll") for (int fn = 0; fn < 2; ++fn)                        \
        _Pragma("unroll") for (int kk = 0; kk < 2; ++kk)                      \
          BS[fn][kk] = *(const s8v*)(bb + fn * 2048 + kk * 1024); }

#define MM(qm, qn, BS)                                                        \
    _Pragma("unroll") for (int kk = 0; kk < 2; ++kk)                          \
      _Pragma("unroll") for (int fm = 0; fm < 4; ++fm)                        \
        _Pragma("unroll") for (int fn = 0; fn < 2; ++fn)                      \
          acc[(qm)*4+fm][(qn)*2+fn] = __builtin_amdgcn_mfma_f32_16x16x32_bf16(\
            aset[fm][kk], BS[fn][kk], acc[(qm)*4+fm][(qn)*2+fn], 0, 0, 0);

    // ---- prologue: stage tile 0 (buf0), drain, barrier ----
    STAGE(0, pA0);  // A0
    STAGE(2, pB0);  // B0
    STAGE(3, pB1);  // B1
    STAGE(1, pA1);  // A1
    WAITVM(0);
    BARX();

    for (int t = 0; t < NT - 1; ++t) {
        const int buf4 = (t & 1) * 4;
        const int nb4  = ((t + 1) & 1) * 4;

        // ---- ph0 ----
        RD_A(0); RD_B(0, b0set);
        STAGE(nb4 + 0, pA0);
        __builtin_amdgcn_s_setprio(1); MM(0, 0, b0set); __builtin_amdgcn_s_setprio(0);
        WAITVM(4); BARX();

        // ---- ph1 ----
        RD_B(1, b1set);
        STAGE(nb4 + 2, pB0);
        __builtin_amdgcn_s_setprio(1); MM(0, 1, b1set); __builtin_amdgcn_s_setprio(0);
        WAITVM(4); BARX();

        // ---- ph23 ----
        RD_A(1);
        STAGE(nb4 + 3, pB1);
        __builtin_amdgcn_s_setprio(1); MM(1, 1, b1set); __builtin_amdgcn_s_setprio(0);
        STAGE(nb4 + 1, pA1);
        __builtin_amdgcn_s_setprio(1); MM(1, 0, b0set); __builtin_amdgcn_s_setprio(0);
        WAITVM(4); BARX();
    }

    // ---- last tile (no staging; shrinking waits) ----
    {
        const int buf4 = ((NT - 1) & 1) * 4;
        RD_A(0); RD_B(0, b0set);
        __builtin_amdgcn_s_setprio(1); MM(0, 0, b0set); __builtin_amdgcn_s_setprio(0);
        WAITVM(2); BARX();
        RD_B(1, b1set);
        __builtin_amdgcn_s_setprio(1); MM(0, 1, b1set); __builtin_amdgcn_s_setprio(0);
        WAITVM(0); BARX();
        RD_A(1);
        __builtin_amdgcn_s_setprio(1); MM(1, 1, b1set); MM(1, 0, b0set);
        __builtin_amdgcn_s_setprio(0);
    }

    // ---- epilogue: D col = lane&15, row = (lane>>4)*4 + r ----
#pragma unroll
    for (int m8 = 0; m8 < 8; ++m8) {
        const int grow = bm0 + (m8 >> 2) * 128 + wm * 64 + (m8 & 3) * 16 + (lane >> 4) * 4;
#pragma unroll
        for (int n4 = 0; n4 < 4; ++n4) {
            const int gcol = bn0 + (n4 >> 1) * 128 + wn * 32 + (n4 & 1) * 16 + (lane & 15);
            float* yp = Cp + (size_t)grow * N_DIM + gcol;
#pragma unroll
            for (int r = 0; r < 4; ++r) yp[(size_t)r * N_DIM] = acc[m8][n4][r];
        }
    }
#undef STAGE
#undef RD_A
#undef RD_B
#undef MM
}

// ---------------- fallback: fused dequant GEMM (no workspace needed) ----------------
__global__ void gemm_fused_kernel(const float* __restrict__ X,
                                  const int* __restrict__ W,
                                  const float* __restrict__ am,
                                  float* __restrict__ C) {
    __shared__ __attribute__((aligned(16))) unsigned short ldsA[128 * 32];
    __shared__ __attribute__((aligned(16))) unsigned short ldsB[128 * 32];
    __shared__ float lut[16];

    const int tid = threadIdx.x;
    if (tid < 16) lut[tid] = NF4C[tid];
    __syncthreads();

    const int wave = tid >> 6, lane = tid & 63;
    const int wr = wave >> 1, wc = wave & 1;
    const int bid = blockIdx.x;
    const int wg  = (bid & 7) * 1024 + (bid >> 3);
    const int bm0 = (wg >> 7) * 128;
    const int bn0 = (wg & 127) * 128;

    const int row = tid >> 2, col8 = (tid & 3) * 8;
    const float* gX0 = X + (size_t)(bm0 + row) * K_DIM + col8;
    const float* gX1 = gX0 + (size_t)64 * K_DIM;
    const int*   gW0 = W + (size_t)(bn0 + row) * K_DIM + col8;
    const int*   gW1 = gW0 + (size_t)64 * K_DIM;
    const int amRow0 = (bn0 + row) * (K_DIM / QBLK);
    const int amRow1 = (bn0 + row + 64) * (K_DIM / QBLK);

    unsigned short* sA0 = ldsA + tid * 8;
    unsigned short* sA1 = ldsA + (tid + 256) * 8;
    unsigned short* sB0 = ldsB + tid * 8;
    unsigned short* sB1 = ldsB + (tid + 256) * 8;

    f4v acc[4][4];
#pragma unroll
    for (int i = 0; i < 4; ++i)
#pragma unroll
        for (int j = 0; j < 4; ++j) acc[i][j] = f4v{0.f, 0.f, 0.f, 0.f};

    const int fr = lane & 15, kg = lane >> 4;
    const unsigned short* pa = ldsA + (wr * 64 + fr) * 32 + kg * 8;
    const unsigned short* pb = ldsB + (wc * 64 + fr) * 32 + kg * 8;

    for (int k0 = 0; k0 < K_DIM; k0 += 32) {
        float4 x0a = *(const float4*)(gX0 + k0);
        float4 x0b = *(const float4*)(gX0 + k0 + 4);
        float4 x1a = *(const float4*)(gX1 + k0);
        float4 x1b = *(const float4*)(gX1 + k0 + 4);
        int4 w0a = *(const int4*)(gW0 + k0);
        int4 w0b = *(const int4*)(gW0 + k0 + 4);
        int4 w1a = *(const int4*)(gW1 + k0);
        int4 w1b = *(const int4*)(gW1 + k0 + 4);
        float s0 = am[amRow0 + ((k0 + col8) >> 6)];
        float s1 = am[amRow1 + ((k0 + col8) >> 6)];

        u16x8 A0, A1, B0, B1;
        A0[0] = f2bf(x0a.x); A0[1] = f2bf(x0a.y); A0[2] = f2bf(x0a.z); A0[3] = f2bf(x0a.w);
        A0[4] = f2bf(x0b.x); A0[5] = f2bf(x0b.y); A0[6] = f2bf(x0b.z); A0[7] = f2bf(x0b.w);
        A1[0] = f2bf(x1a.x); A1[1] = f2bf(x1a.y); A1[2] = f2bf(x1a.z); A1[3] = f2bf(x1a.w);
        A1[4] = f2bf(x1b.x); A1[5] = f2bf(x1b.y); A1[6] = f2bf(x1b.z); A1[7] = f2bf(x1b.w);
        B0[0] = f2bf(lut[w0a.x] * s0); B0[1] = f2bf(lut[w0a.y] * s0);
        B0[2] = f2bf(lut[w0a.z] * s0); B0[3] = f2bf(lut[w0a.w] * s0);
        B0[4] = f2bf(lut[w0b.x] * s0); B0[5] = f2bf(lut[w0b.y] * s0);
        B0[6] = f2bf(lut[w0b.z] * s0); B0[7] = f2bf(lut[w0b.w] * s0);
        B1[0] = f2bf(lut[w1a.x] * s1); B1[1] = f2bf(lut[w1a.y] * s1);
        B1[2] = f2bf(lut[w1a.z] * s1); B1[3] = f2bf(lut[w1a.w] * s1);
        B1[4] = f2bf(lut[w1b.x] * s1); B1[5] = f2bf(lut[w1b.y] * s1);
        B1[6] = f2bf(lut[w1b.z] * s1); B1[7] = f2bf(lut[w1b.w] * s1);

        __syncthreads();
        *(u16x8*)sA0 = A0; *(u16x8*)sA1 = A1;
        *(u16x8*)sB0 = B0; *(u16x8*)sB1 = B1;
        __syncthreads();

        s8v a[4], b[4];
#pragma unroll
        for (int i = 0; i < 4; ++i) a[i] = *(const s8v*)(pa + i * 16 * 32);
#pragma unroll
        for (int i = 0; i < 4; ++i) b[i] = *(const s8v*)(pb + i * 16 * 32);
#pragma unroll
        for (int i = 0; i < 4; ++i)
#pragma unroll
            for (int j = 0; j < 4; ++j)
                acc[i][j] = __builtin_amdgcn_mfma_f32_16x16x32_bf16(a[i], b[j], acc[i][j], 0, 0, 0);
    }

    const int row0 = bm0 + wr * 64 + (lane >> 4) * 4;
    const int col0 = bn0 + wc * 64 + (lane & 15);
#pragma unroll
    for (int i = 0; i < 4; ++i)
#pragma unroll
        for (int j = 0; j < 4; ++j) {
            float* yp = C + (size_t)(row0 + i * 16) * N_DIM + col0 + j * 16;
#pragma unroll
            for (int r = 0; r < 4; ++r) yp[(size_t)r * N_DIM] = acc[i][j][r];
        }
}

extern "C" void kernel_launch(void* const* d_in, const int* in_sizes, int n_in,
                              void* d_out, int out_size, void* d_ws, size_t ws_size,
                              hipStream_t stream) {
    const float* x     = (const float*)d_in[0];
    const int*   codes = (const int*)d_in[1];
    const float* am    = (const float*)d_in[2];
    float* y = (float*)d_out;

    const long MK = (long)M_DIM * K_DIM;
    const long NK = (long)N_DIM * K_DIM;
    const size_t need = (size_t)(MK + NK) * sizeof(unsigned short);  // 192 MiB

    if (ws_size >= need) {
        unsigned short* xb = (unsigned short*)d_ws;
        unsigned short* wb = xb + MK;
        convert_x_kernel<<<2048, 256, 0, stream>>>(x, xb, MK);
        dequant_w_kernel<<<2048, 256, 0, stream>>>(codes, am, wb, NK);
        const int ngrid = (M_DIM / BM) * (N_DIM / BN);  // 2048
        gemm_3phase_kernel<<<ngrid, 512, 0, stream>>>(xb, wb, y);
    } else {
        const int ngrid = (M_DIM / 128) * (N_DIM / 128); // 8192
        gemm_fused_kernel<<<ngrid, 256, 0, stream>>>(x, codes, am, y);
    }
}